// Round 9
// baseline (257.361 us; speedup 1.0000x reference)
//
#include <hip/hip_runtime.h>

#define TC 128
#define KD 64
#define WLOG_MIN (-5.2983174f)   // ln(0.005)

typedef __attribute__((ext_vector_type(8))) short short8;
typedef __attribute__((ext_vector_type(4))) short short4_t;
typedef __attribute__((ext_vector_type(4))) float f32x4;

__device__ __forceinline__ unsigned short f2bf(float x) {
  union { float f; unsigned int u; } c; c.f = x;
  unsigned int u = c.u + 0x7fffu + ((c.u >> 16) & 1u);   // RNE
  return (unsigned short)(u >> 16);
}
__device__ __forceinline__ float bf2f(unsigned short x) {
  union { unsigned int u; float f; } c; c.u = ((unsigned int)x) << 16; return c.f;
}
__device__ __forceinline__ f32x4 shfl4(f32x4 v, int src) {
  f32x4 r;
  #pragma unroll
  for (int i = 0; i < 4; ++i) r[i] = __shfl(v[i], src, 64);
  return r;
}

// Staging thread map (both kernels): lane = (q = lane>>4, c4 = lane&15).
// Lane owns cols kd0..kd0+3 (kd0 = c4*4) x rows t = wv*16 + q*4 + j (j<4).
// -> ALL input loads are global_load_dwordx4 (1 KB/wave/instr vs 256 B
//    scalar; rounds 4-6 proved the compiler won't raise scalar-load MLP).
// rd/ki swizzle: elem (t,kd) at t*64 + (slot<<3 | kd&7),
//   slot = (kd>>3)^(t&7)^((t>>3)&7); per-lane 4 cols = one b64 store.
// vT/kiT/sT swizzle: (t,kd) at kd*TC + ((g^(kd&7))<<3) + (t&7), g=t>>3;
//   lane's 4 rows = positions (q&1)*4+j -> one b64 store per col.
// Cumsum: in-lane serial over 4 rows + quad-prefix via shfl (ulp-level
// addition-order change vs old serial-16; threshold headroom 0.25/0.775).

// ---------------------------------------------------------------------------
// K1 (wkv/wse producer): per-(b,h,chunk), 512 thr. dwordx4 loads of k,v,w;
// stages kiT/vT; 2 wkv tiles per wave; writes wkv bf16 + wse.
// LDS 34,816 B -> 4 blocks/CU (VGPR capped 64 by bounds(512,8)).
// ---------------------------------------------------------------------------
__global__ __launch_bounds__(512, 8)
void rwkv_wkv(const float* __restrict__ kk_, const float* __restrict__ vv,
              const float* __restrict__ ww,
              unsigned short* __restrict__ wkv_u16, float* __restrict__ wse_ws,
              int N) {
  __shared__ alignas(16) unsigned short vT_s[KD * TC];
  __shared__ alignas(16) unsigned short kiT_s[KD * TC];
  __shared__ alignas(16) float segtot[8 * 64];

  const int bid = blockIdx.x;
  const int n = bid % N, bh = bid / N;
  const size_t base = ((size_t)bh * N + n) * (TC * KD);
  const float *kg = kk_ + base, *vg = vv + base, *wg = ww + base;

  const int tid = threadIdx.x;
  const int lane = tid & 63, wv = tid >> 6;
  const int q = lane >> 4, c4 = lane & 15, kd0 = c4 * 4;

  // ---- dwordx4 loads ----
  f32x4 wl4[4], k4[4], v4[4];
  #pragma unroll
  for (int j = 0; j < 4; ++j) {
    const int t = wv * 16 + q * 4 + j;
    wl4[j] = *(const f32x4*)&wg[t * KD + kd0];
    k4[j] = *(const f32x4*)&kg[t * KD + kd0];
    v4[j] = *(const f32x4*)&vg[t * KD + kd0];
  }
  #pragma unroll
  for (int j = 0; j < 4; ++j)
    #pragma unroll
    for (int i = 0; i < 4; ++i) wl4[j][i] = fmaxf(wl4[j][i], WLOG_MIN);

  // ---- pass 1: in-lane serial col-sums + quad prefix/totals via shfl ----
  const f32x4 ls = ((wl4[0] + wl4[1]) + wl4[2]) + wl4[3];
  const f32x4 s0 = shfl4(ls, c4), s1 = shfl4(ls, 16 + c4);
  const f32x4 s2 = shfl4(ls, 32 + c4), s3 = shfl4(ls, 48 + c4);
  const f32x4 zero = {0.f, 0.f, 0.f, 0.f};
  f32x4 pre = (q > 0 ? s0 : zero);
  pre += (q > 1 ? s1 : zero);
  pre += (q > 2 ? s2 : zero);
  const f32x4 tot = ((s0 + s1) + s2) + s3;
  if (q == 0) *(f32x4*)&segtot[wv * 64 + kd0] = tot;
  __syncthreads();

  f32x4 segofs4 = zero, myoff4 = zero, wsum4 = zero;
  #pragma unroll
  for (int i = 0; i < 8; ++i) {
    const f32x4 si = *(const f32x4*)&segtot[i * 64 + kd0];
    if (i < wv) segofs4 += si;
    if (i < 4) myoff4 += si;
    wsum4 += si;
  }
  f32x4 wsoff4;
  #pragma unroll
  for (int i = 0; i < 4; ++i) wsoff4[i] = __expf(wsum4[i] - myoff4[i]);
  if (wv == 0 && q == 0) {
    f32x4 e;
    #pragma unroll
    for (int i = 0; i < 4; ++i) e[i] = __expf(wsum4[i]);
    *(f32x4*)&wse_ws[((size_t)bh * N + n) * KD + kd0] = e;
  }

  // ---- pass 2: stage ki^T, v^T (b64 stores) ----
  {
    f32x4 cc = segofs4 + pre;
    short4_t kib[4], vb[4];
    #pragma unroll
    for (int j = 0; j < 4; ++j) {
      #pragma unroll
      for (int i = 0; i < 4; ++i) {
        kib[i][j] = (short)f2bf(k4[j][i] * __expf(myoff4[i] - cc[i] - wl4[j][i]));
        vb[i][j] = (short)f2bf(v4[j][i]);
      }
      cc += wl4[j];
    }
    const int g = wv * 2 + (q >> 1), p4 = (q & 1) * 4;
    #pragma unroll
    for (int i = 0; i < 4; ++i) {
      const int kd = kd0 + i;
      *(short4_t*)&kiT_s[kd * TC + ((g ^ (kd & 7)) << 3) + p4] = kib[i];
      *(short4_t*)&vT_s[kd * TC + ((g ^ (kd & 7)) << 3) + p4] = vb[i];
    }
  }
  __syncthreads();

  // ---- wkv = (ki * w_inter)^T @ v -> bf16 (2 of 16 tiles per wave) ----
  {
    const int quad = lane >> 4, l16 = lane & 15;
    const int kt = wv >> 1;             // kd-tile 0..3
    const int nb = (wv & 1) * 2;        // vd-tile base
    f32x4 acc[2] = {{0,0,0,0},{0,0,0,0}};
    const int row = kt * 16 + l16;      // kd row of ki^T
    #pragma unroll
    for (int ks = 0; ks < 4; ++ks) {
      short8 a = *(const short8*)&kiT_s[row * TC + (((ks * 4 + quad) ^ (row & 7)) << 3)];
      #pragma unroll
      for (int nn = 0; nn < 2; ++nn) {
        const int vd = (nb + nn) * 16 + l16;
        short8 b = *(const short8*)&vT_s[vd * TC + (((ks * 4 + quad) ^ (vd & 7)) << 3)];
        acc[nn] = __builtin_amdgcn_mfma_f32_16x16x32_bf16(a, b, acc[nn], 0, 0, 0);
      }
    }
    // col x = kt*16+quad*4+reg lives at lane x>>2 = kt*4+quad, comp x&3 = reg
    float wso[4];
    #pragma unroll
    for (int reg = 0; reg < 4; ++reg) wso[reg] = __shfl(wsoff4[reg], kt * 4 + quad, 64);
    unsigned short* wkvg = wkv_u16 + ((size_t)bh * N + n) * (KD * KD);
    #pragma unroll
    for (int nn = 0; nn < 2; ++nn)
      #pragma unroll
      for (int reg = 0; reg < 4; ++reg)
        wkvg[(kt * 16 + quad * 4 + reg) * KD + (nb + nn) * 16 + l16] = f2bf(acc[nn][reg] * wso[reg]);
  }
}

// ---------------------------------------------------------------------------
// K2 (main): per-(b,h,chunk), 512 thr. dwordx4 loads of r/k/v/w; intra A@v
// -> regs; scans wkv prefix (L3-hot) -> S_n; out = intra + rw@S_n, single
// pure-write store. segtot + Ast alias dead regions of rd_s: LDS 49,408 B
// -> 3 blocks/CU (24 waves/CU; was 2 blocks at 59,904).
// ---------------------------------------------------------------------------
__global__ __launch_bounds__(512, 6)
void rwkv_main(const float* __restrict__ rr, const float* __restrict__ kk_,
               const float* __restrict__ vv, const float* __restrict__ ww,
               const float* __restrict__ uu,
               const unsigned short* __restrict__ wkv_u16,
               const float* __restrict__ wse_ws,
               const float* __restrict__ st_in,
               float* __restrict__ out, float* __restrict__ final_out,
               int H, int N) {
  __shared__ alignas(16) unsigned short rd_s[TC * KD];  // aliases segtot + per-wave Ast
  __shared__ alignas(16) unsigned short ki_s[TC * KD];
  __shared__ alignas(16) unsigned short vT_s[KD * TC];
  __shared__ alignas(16) unsigned short diag_s[TC];
  float* segtot = (float*)rd_s;   // pass-1 only; consumed before rd_s staged

  const int bid = blockIdx.x;
  const int n = bid % N, bh = bid / N, h = bh % H;
  const size_t base = ((size_t)bh * N + n) * (TC * KD);
  const float *rg = rr + base, *kg = kk_ + base, *vg = vv + base, *wg = ww + base;

  const int tid = threadIdx.x;
  const int lane = tid & 63, wv = tid >> 6;
  const int q = lane >> 4, c4 = lane & 15, kd0 = c4 * 4;
  const int quad = lane >> 4, l16 = lane & 15;
  const f32x4 uk4 = *(const f32x4*)&uu[h * KD + kd0];

  // ---- dwordx4 loads ----
  f32x4 wl4[4], r4[4], k4[4], v4[4];
  #pragma unroll
  for (int j = 0; j < 4; ++j) {
    const int t = wv * 16 + q * 4 + j;
    wl4[j] = *(const f32x4*)&wg[t * KD + kd0];
    r4[j] = *(const f32x4*)&rg[t * KD + kd0];
    k4[j] = *(const f32x4*)&kg[t * KD + kd0];
    v4[j] = *(const f32x4*)&vg[t * KD + kd0];
  }
  #pragma unroll
  for (int j = 0; j < 4; ++j)
    #pragma unroll
    for (int i = 0; i < 4; ++i) wl4[j][i] = fmaxf(wl4[j][i], WLOG_MIN);

  // ---- pass 1 ----
  const f32x4 ls = ((wl4[0] + wl4[1]) + wl4[2]) + wl4[3];
  const f32x4 s0 = shfl4(ls, c4), s1 = shfl4(ls, 16 + c4);
  const f32x4 s2 = shfl4(ls, 32 + c4), s3 = shfl4(ls, 48 + c4);
  const f32x4 zero = {0.f, 0.f, 0.f, 0.f};
  f32x4 pre = (q > 0 ? s0 : zero);
  pre += (q > 1 ? s1 : zero);
  pre += (q > 2 ? s2 : zero);
  const f32x4 tot = ((s0 + s1) + s2) + s3;
  if (q == 0) *(f32x4*)&segtot[wv * 64 + kd0] = tot;
  __syncthreads();
  f32x4 segofs4 = zero, myoff4 = zero;
  #pragma unroll
  for (int i = 0; i < 8; ++i) {
    const f32x4 si = *(const f32x4*)&segtot[i * 64 + kd0];
    if (i < wv) segofs4 += si;
    if (i < 4) myoff4 += si;
  }
  __syncthreads();   // segtot (aliased in rd_s) fully read before rd_s staged
  f32x4 eoff4;
  #pragma unroll
  for (int i = 0; i < 4; ++i) eoff4[i] = __expf(myoff4[i]);

  // ---- pass 2: staging (rd_s, ki_s, vT_s b64; rw->regs; diag->LDS) ----
  short4_t rwq[4];
  {
    f32x4 cc = segofs4 + pre;
    short4_t vb[4];
    float dar[4];
    #pragma unroll
    for (int j = 0; j < 4; ++j) {
      const int t = wv * 16 + q * 4 + j;
      const int addr = t * KD + (((c4 >> 1) ^ (t & 7) ^ ((t >> 3) & 7)) << 3) + (c4 & 1) * 4;
      short4_t rdv, kiv;
      #pragma unroll
      for (int i = 0; i < 4; ++i) {
        const float e1 = __expf(cc[i] - myoff4[i]);
        rdv[i] = (short)f2bf(r4[j][i] * e1);
        rwq[j][i] = (short)f2bf(r4[j][i] * e1 * eoff4[i]);
        kiv[i] = (short)f2bf(k4[j][i] * __expf(myoff4[i] - cc[i] - wl4[j][i]));
        vb[i][j] = (short)f2bf(v4[j][i]);
      }
      *(short4_t*)&rd_s[addr] = rdv;
      *(short4_t*)&ki_s[addr] = kiv;
      dar[j] = r4[j][0] * uk4[0] * k4[j][0];
      dar[j] += r4[j][1] * uk4[1] * k4[j][1];
      dar[j] += r4[j][2] * uk4[2] * k4[j][2];
      dar[j] += r4[j][3] * uk4[3] * k4[j][3];
      cc += wl4[j];
    }
    const int g = wv * 2 + (q >> 1), p4 = (q & 1) * 4;
    #pragma unroll
    for (int i = 0; i < 4; ++i) {
      const int kd = kd0 + i;
      *(short4_t*)&vT_s[kd * TC + ((g ^ (kd & 7)) << 3) + p4] = vb[i];
    }
    // diag: 16-lane butterfly over c4 (cols), 4 rows batched
    #pragma unroll
    for (int o = 8; o > 0; o >>= 1)
      #pragma unroll
      for (int j = 0; j < 4; ++j) dar[j] += __shfl_xor(dar[j], o, 64);
    if (c4 == 0) {
      short4_t dp;
      #pragma unroll
      for (int j = 0; j < 4; ++j) dp[j] = (short)f2bf(dar[j]);
      *(short4_t*)&diag_s[wv * 16 + q * 4] = dp;
    }
  }
  __syncthreads();

  // ---- scan prefix (b128 global reads; issue early, hide under intra) ----
  const int skd = tid >> 3, sv0 = (tid & 7) * 8;
  const size_t sbase = (size_t)bh * (KD * KD);
  float s[8];
  *(f32x4*)&s[0] = *(const f32x4*)&st_in[sbase + skd * KD + sv0];
  *(f32x4*)&s[4] = *(const f32x4*)&st_in[sbase + skd * KD + sv0 + 4];
  const float* wseb = wse_ws + (size_t)bh * N * KD + skd;
  const unsigned short* wkvb = wkv_u16 + (size_t)bh * N * (KD * KD) + skd * KD + sv0;
  {
    float e_c = 0.f; short8 x_c = {0};
    if (n > 0) {
      e_c = wseb[0];
      x_c = *(const short8*)&wkvb[0];
    }
    for (int j = 0; j < n; ++j) {
      const float e = e_c; const short8 x = x_c;
      if (j + 1 < n) {
        e_c = wseb[(size_t)(j + 1) * KD];
        x_c = *(const short8*)&wkvb[(size_t)(j + 1) * (KD * KD)];
      }
      #pragma unroll
      for (int i = 0; i < 8; ++i) s[i] = s[i] * e + bf2f((unsigned short)x[i]);
    }
  }

  // ---- intra: fused A^T tiles + A@v -> oacc regs (one ib per wave) ----
  f32x4 oacc[4];
  {
    const int ib = wv, i0 = ib * 16, irow = i0 + l16;
    const int rsw = (irow & 7) ^ ((irow >> 3) & 7);
    short8 b0 = *(const short8*)&rd_s[irow * KD + ((quad ^ rsw) << 3)];
    short8 b1 = *(const short8*)&rd_s[irow * KD + (((4 + quad) ^ rsw) << 3)];
    const float diag_i = bf2f(diag_s[irow]);
    #pragma unroll
    for (int nn = 0; nn < 4; ++nn) oacc[nn] = (f32x4){0, 0, 0, 0};
    const int npairs = (ib + 2) >> 1;
    // Ast aliases this wave's OWN rd_s segment (rows wv*16..+16, 2048 B >=
    // 1280 B needed). b0/b1 are read before the first Ast write (program
    // order, same wave); no other wave touches this segment.
    unsigned short* astw = &rd_s[wv * 16 * KD];
    for (int jp = 0; jp < npairs; ++jp) {
      #pragma unroll
      for (int jj = 0; jj < 2; ++jj) {
        const int j = jp * 2 + jj;
        short4_t pk;
        if (j <= ib) {
          const int jrow = j * 16 + l16;
          const int jsw = (jrow & 7) ^ ((jrow >> 3) & 7);
          short8 a0 = *(const short8*)&ki_s[jrow * KD + ((quad ^ jsw) << 3)];
          short8 a1 = *(const short8*)&ki_s[jrow * KD + (((4 + quad) ^ jsw) << 3)];
          f32x4 at = {0, 0, 0, 0};
          at = __builtin_amdgcn_mfma_f32_16x16x32_bf16(a0, b0, at, 0, 0, 0);
          at = __builtin_amdgcn_mfma_f32_16x16x32_bf16(a1, b1, at, 0, 0, 0);
          #pragma unroll
          for (int reg = 0; reg < 4; ++reg) {
            const int je = j * 16 + quad * 4 + reg;
            float val = at[reg];
            if (j == ib) val = (je < irow) ? val : ((je == irow) ? diag_i : 0.f);
            pk[reg] = (short)f2bf(val);
          }
        } else {
          pk = (short4_t)0;  // guard half for even ib
        }
        *(short4_t*)&astw[l16 * 40 + jj * 16 + quad * 4] = pk;
      }
      short8 af = *(const short8*)&astw[l16 * 40 + quad * 8];
      #pragma unroll
      for (int nn = 0; nn < 4; ++nn) {
        const int vd = nn * 16 + l16;
        short8 bv = *(const short8*)&vT_s[vd * TC + (((jp * 4 + quad) ^ (vd & 7)) << 3)];
        oacc[nn] = __builtin_amdgcn_mfma_f32_16x16x32_bf16(af, bv, oacc[nn], 0, 0, 0);
      }
    }
  }
  __syncthreads();   // staging LDS dead; safe to repurpose

  // ---- sT -> ki_s[0..4096), rw regs -> rd_s (swizzled b64) ----
  {
    const int g = skd >> 3, k7 = skd & 7;
    #pragma unroll
    for (int i = 0; i < 8; ++i) {
      const int vd = sv0 + i;
      ki_s[vd * KD + (((g ^ (vd & 7)) << 3) | k7)] = f2bf(s[i]);
    }
  }
  #pragma unroll
  for (int j = 0; j < 4; ++j) {
    const int t = wv * 16 + q * 4 + j;
    const int addr = t * KD + (((c4 >> 1) ^ (t & 7) ^ ((t >> 3) & 7)) << 3) + (c4 & 1) * 4;
    *(short4_t*)&rd_s[addr] = rwq[j];
  }
  if (n == N - 1) {   // final state: one more step then store
    const float e = wseb[(size_t)n * KD];
    const short8 x = *(const short8*)&wkvb[(size_t)n * (KD * KD)];
    #pragma unroll
    for (int i = 0; i < 8; ++i) s[i] = s[i] * e + bf2f((unsigned short)x[i]);
    *(f32x4*)&final_out[sbase + skd * KD + sv0] = *(const f32x4*)&s[0];
    *(f32x4*)&final_out[sbase + skd * KD + sv0 + 4] = *(const f32x4*)&s[4];
  }
  __syncthreads();

  // ---- inter = rw @ S_n; out = intra + inter, single pure-write store ----
  {
    const int ib = wv, trow = ib * 16 + l16;
    const int rsw = (trow & 7) ^ ((trow >> 3) & 7);
    short8 a0 = *(const short8*)&rd_s[trow * KD + ((quad ^ rsw) << 3)];
    short8 a1 = *(const short8*)&rd_s[trow * KD + (((4 + quad) ^ rsw) << 3)];
    float* og = out + base;
    #pragma unroll
    for (int nn = 0; nn < 4; ++nn) {
      const int vd = nn * 16 + l16;
      short8 b0 = *(const short8*)&ki_s[vd * KD + ((quad ^ (vd & 7)) << 3)];
      short8 b1 = *(const short8*)&ki_s[vd * KD + (((4 + quad) ^ (vd & 7)) << 3)];
      f32x4 acc = {0, 0, 0, 0};
      acc = __builtin_amdgcn_mfma_f32_16x16x32_bf16(a0, b0, acc, 0, 0, 0);
      acc = __builtin_amdgcn_mfma_f32_16x16x32_bf16(a1, b1, acc, 0, 0, 0);
      #pragma unroll
      for (int reg = 0; reg < 4; ++reg)
        og[(size_t)(ib * 16 + quad * 4 + reg) * KD + nn * 16 + l16] = oacc[nn][reg] + acc[reg];
    }
  }
}

// ---------------------------------------------------------------------------
// Workspace (~8.9 MB): [wkv u16: BH*N*K*K][wse f32: BH*N*K]
// ---------------------------------------------------------------------------
extern "C" void kernel_launch(void* const* d_in, const int* in_sizes, int n_in,
                              void* d_out, int out_size, void* d_ws, size_t ws_size,
                              hipStream_t stream) {
  const float* r = (const float*)d_in[0];
  const float* k = (const float*)d_in[1];
  const float* v = (const float*)d_in[2];
  const float* w = (const float*)d_in[3];
  const float* u = (const float*)d_in[4];
  const float* st0 = (const float*)d_in[5];
  float* out = (float*)d_out;

  const int BH = in_sizes[5] / (KD * KD);  // 64
  const int H = in_sizes[4] / KD;          // 16
  const int T = in_sizes[0] / (BH * KD);   // 2048
  const int N = T / TC;                    // 16

  unsigned short* wkv_u16 = (unsigned short*)d_ws;
  float* wse_ws = (float*)(wkv_u16 + (size_t)BH * N * KD * KD);
  float* final_out = out + (size_t)in_sizes[0];

  rwkv_wkv<<<BH * N, 512, 0, stream>>>(k, v, w, wkv_u16, wse_ws, N);
  rwkv_main<<<BH * N, 512, 0, stream>>>(r, k, v, w, u, wkv_u16, wse_ws, st0,
                                        out, final_out, H, N);
}

// Round 10
// 215.172 us; speedup vs baseline: 1.1961x; 1.1961x over previous
//
#include <hip/hip_runtime.h>

#define TC 128
#define KD 64
#define WLOG_MIN (-5.2983174f)   // ln(0.005)

typedef __attribute__((ext_vector_type(8))) short short8;
typedef __attribute__((ext_vector_type(4))) short short4_t;
typedef __attribute__((ext_vector_type(4))) float f32x4;

__device__ __forceinline__ unsigned short f2bf(float x) {
  union { float f; unsigned int u; } c; c.f = x;
  unsigned int u = c.u + 0x7fffu + ((c.u >> 16) & 1u);   // RNE
  return (unsigned short)(u >> 16);
}
__device__ __forceinline__ float bf2f(unsigned short x) {
  union { unsigned int u; float f; } c; c.u = ((unsigned int)x) << 16; return c.f;
}
__device__ __forceinline__ f32x4 shfl4(f32x4 v, int src) {
  f32x4 r;
  #pragma unroll
  for (int i = 0; i < 4; ++i) r[i] = __shfl(v[i], src, 64);
  return r;
}

// Staging thread map (both kernels): lane = (q = lane>>4, c4 = lane&15).
// Lane owns cols kd0..kd0+3 (kd0 = c4*4) x rows t = wv*16 + q*4 + j (j<4).
// -> ALL input loads are global_load_dwordx4 (1 KB/wave/instr).
// REGISTER BUDGET (round 9 lesson): the staged f32x4 arrays need ~64 VGPRs
// live; launch_bounds caps below ~100 (main) / ~75 (wkv) cause scratch
// spill: round 9's (512,6)+(512,8) showed VGPR=40 and +160 MB of spill
// traffic (WRITE 138 MB). main=(512,4): 128-reg cap, 2 blk/CU.
// wkv=(512,6): ~85-reg cap, 3 blk/CU.
// rd/ki swizzle: elem (t,kd) at t*64 + (slot<<3 | kd&7),
//   slot = (kd>>3)^(t&7)^((t>>3)&7); per-lane 4 cols = one b64 store.
// vT/kiT/sT swizzle: (t,kd) at kd*TC + ((g^(kd&7))<<3) + (t&7), g=t>>3.
// Cumsum: in-lane serial over 4 rows + quad-prefix via shfl (ulp-level
// addition-order change vs serial-16; threshold headroom 0.25/0.775).

// ---------------------------------------------------------------------------
// K1 (wkv/wse producer): per-(b,h,chunk), 512 thr. dwordx4 loads of k,v,w;
// stages kiT/vT; 2 wkv tiles per wave; writes wkv bf16 + wse.
// ---------------------------------------------------------------------------
__global__ __launch_bounds__(512, 6)
void rwkv_wkv(const float* __restrict__ kk_, const float* __restrict__ vv,
              const float* __restrict__ ww,
              unsigned short* __restrict__ wkv_u16, float* __restrict__ wse_ws,
              int N) {
  __shared__ alignas(16) unsigned short vT_s[KD * TC];
  __shared__ alignas(16) unsigned short kiT_s[KD * TC];
  __shared__ alignas(16) float segtot[8 * 64];

  const int bid = blockIdx.x;
  const int n = bid % N, bh = bid / N;
  const size_t base = ((size_t)bh * N + n) * (TC * KD);
  const float *kg = kk_ + base, *vg = vv + base, *wg = ww + base;

  const int tid = threadIdx.x;
  const int lane = tid & 63, wv = tid >> 6;
  const int q = lane >> 4, c4 = lane & 15, kd0 = c4 * 4;

  // ---- dwordx4 loads ----
  f32x4 wl4[4], k4[4], v4[4];
  #pragma unroll
  for (int j = 0; j < 4; ++j) {
    const int t = wv * 16 + q * 4 + j;
    wl4[j] = *(const f32x4*)&wg[t * KD + kd0];
    k4[j] = *(const f32x4*)&kg[t * KD + kd0];
    v4[j] = *(const f32x4*)&vg[t * KD + kd0];
  }
  #pragma unroll
  for (int j = 0; j < 4; ++j)
    #pragma unroll
    for (int i = 0; i < 4; ++i) wl4[j][i] = fmaxf(wl4[j][i], WLOG_MIN);

  // ---- pass 1: in-lane serial col-sums + quad prefix/totals via shfl ----
  const f32x4 ls = ((wl4[0] + wl4[1]) + wl4[2]) + wl4[3];
  const f32x4 s0 = shfl4(ls, c4), s1 = shfl4(ls, 16 + c4);
  const f32x4 s2 = shfl4(ls, 32 + c4), s3 = shfl4(ls, 48 + c4);
  const f32x4 zero = {0.f, 0.f, 0.f, 0.f};
  f32x4 pre = (q > 0 ? s0 : zero);
  pre += (q > 1 ? s1 : zero);
  pre += (q > 2 ? s2 : zero);
  const f32x4 tot = ((s0 + s1) + s2) + s3;
  if (q == 0) *(f32x4*)&segtot[wv * 64 + kd0] = tot;
  __syncthreads();

  f32x4 segofs4 = zero, myoff4 = zero, wsum4 = zero;
  #pragma unroll
  for (int i = 0; i < 8; ++i) {
    const f32x4 si = *(const f32x4*)&segtot[i * 64 + kd0];
    if (i < wv) segofs4 += si;
    if (i < 4) myoff4 += si;
    wsum4 += si;
  }
  f32x4 wsoff4;
  #pragma unroll
  for (int i = 0; i < 4; ++i) wsoff4[i] = __expf(wsum4[i] - myoff4[i]);
  if (wv == 0 && q == 0) {
    f32x4 e;
    #pragma unroll
    for (int i = 0; i < 4; ++i) e[i] = __expf(wsum4[i]);
    *(f32x4*)&wse_ws[((size_t)bh * N + n) * KD + kd0] = e;
  }

  // ---- pass 2: stage ki^T, v^T (b64 stores) ----
  {
    f32x4 cc = segofs4 + pre;
    short4_t kib[4], vb[4];
    #pragma unroll
    for (int j = 0; j < 4; ++j) {
      #pragma unroll
      for (int i = 0; i < 4; ++i) {
        kib[i][j] = (short)f2bf(k4[j][i] * __expf(myoff4[i] - cc[i] - wl4[j][i]));
        vb[i][j] = (short)f2bf(v4[j][i]);
      }
      cc += wl4[j];
    }
    const int g = wv * 2 + (q >> 1), p4 = (q & 1) * 4;
    #pragma unroll
    for (int i = 0; i < 4; ++i) {
      const int kd = kd0 + i;
      *(short4_t*)&kiT_s[kd * TC + ((g ^ (kd & 7)) << 3) + p4] = kib[i];
      *(short4_t*)&vT_s[kd * TC + ((g ^ (kd & 7)) << 3) + p4] = vb[i];
    }
  }
  __syncthreads();

  // ---- wkv = (ki * w_inter)^T @ v -> bf16 (2 of 16 tiles per wave) ----
  {
    const int quad = lane >> 4, l16 = lane & 15;
    const int kt = wv >> 1;             // kd-tile 0..3
    const int nb = (wv & 1) * 2;        // vd-tile base
    f32x4 acc[2] = {{0,0,0,0},{0,0,0,0}};
    const int row = kt * 16 + l16;      // kd row of ki^T
    #pragma unroll
    for (int ks = 0; ks < 4; ++ks) {
      short8 a = *(const short8*)&kiT_s[row * TC + (((ks * 4 + quad) ^ (row & 7)) << 3)];
      #pragma unroll
      for (int nn = 0; nn < 2; ++nn) {
        const int vd = (nb + nn) * 16 + l16;
        short8 b = *(const short8*)&vT_s[vd * TC + (((ks * 4 + quad) ^ (vd & 7)) << 3)];
        acc[nn] = __builtin_amdgcn_mfma_f32_16x16x32_bf16(a, b, acc[nn], 0, 0, 0);
      }
    }
    // col x = kt*16+quad*4+reg lives at lane x>>2 = kt*4+quad, comp x&3 = reg
    float wso[4];
    #pragma unroll
    for (int reg = 0; reg < 4; ++reg) wso[reg] = __shfl(wsoff4[reg], kt * 4 + quad, 64);
    unsigned short* wkvg = wkv_u16 + ((size_t)bh * N + n) * (KD * KD);
    #pragma unroll
    for (int nn = 0; nn < 2; ++nn)
      #pragma unroll
      for (int reg = 0; reg < 4; ++reg)
        wkvg[(kt * 16 + quad * 4 + reg) * KD + (nb + nn) * 16 + l16] = f2bf(acc[nn][reg] * wso[reg]);
  }
}

// ---------------------------------------------------------------------------
// K2 (main): per-(b,h,chunk), 512 thr. dwordx4 loads of r/k/v/w; intra A@v
// -> regs; scans wkv prefix (L3-hot) -> S_n; out = intra + rw@S_n, single
// pure-write store. segtot + Ast alias dead regions of rd_s.
// LDS 49,408 B; (512,4): 128-reg cap -> no spill, 2 blocks/CU.
// ---------------------------------------------------------------------------
__global__ __launch_bounds__(512, 4)
void rwkv_main(const float* __restrict__ rr, const float* __restrict__ kk_,
               const float* __restrict__ vv, const float* __restrict__ ww,
               const float* __restrict__ uu,
               const unsigned short* __restrict__ wkv_u16,
               const float* __restrict__ wse_ws,
               const float* __restrict__ st_in,
               float* __restrict__ out, float* __restrict__ final_out,
               int H, int N) {
  __shared__ alignas(16) unsigned short rd_s[TC * KD];  // aliases segtot + per-wave Ast
  __shared__ alignas(16) unsigned short ki_s[TC * KD];
  __shared__ alignas(16) unsigned short vT_s[KD * TC];
  __shared__ alignas(16) unsigned short diag_s[TC];
  float* segtot = (float*)rd_s;   // pass-1 only; consumed before rd_s staged

  const int bid = blockIdx.x;
  const int n = bid % N, bh = bid / N, h = bh % H;
  const size_t base = ((size_t)bh * N + n) * (TC * KD);
  const float *rg = rr + base, *kg = kk_ + base, *vg = vv + base, *wg = ww + base;

  const int tid = threadIdx.x;
  const int lane = tid & 63, wv = tid >> 6;
  const int q = lane >> 4, c4 = lane & 15, kd0 = c4 * 4;
  const int quad = lane >> 4, l16 = lane & 15;
  const f32x4 uk4 = *(const f32x4*)&uu[h * KD + kd0];

  // ---- dwordx4 loads ----
  f32x4 wl4[4], r4[4], k4[4], v4[4];
  #pragma unroll
  for (int j = 0; j < 4; ++j) {
    const int t = wv * 16 + q * 4 + j;
    wl4[j] = *(const f32x4*)&wg[t * KD + kd0];
    r4[j] = *(const f32x4*)&rg[t * KD + kd0];
    k4[j] = *(const f32x4*)&kg[t * KD + kd0];
    v4[j] = *(const f32x4*)&vg[t * KD + kd0];
  }
  #pragma unroll
  for (int j = 0; j < 4; ++j)
    #pragma unroll
    for (int i = 0; i < 4; ++i) wl4[j][i] = fmaxf(wl4[j][i], WLOG_MIN);

  // ---- pass 1 ----
  const f32x4 ls = ((wl4[0] + wl4[1]) + wl4[2]) + wl4[3];
  const f32x4 s0 = shfl4(ls, c4), s1 = shfl4(ls, 16 + c4);
  const f32x4 s2 = shfl4(ls, 32 + c4), s3 = shfl4(ls, 48 + c4);
  const f32x4 zero = {0.f, 0.f, 0.f, 0.f};
  f32x4 pre = (q > 0 ? s0 : zero);
  pre += (q > 1 ? s1 : zero);
  pre += (q > 2 ? s2 : zero);
  const f32x4 tot = ((s0 + s1) + s2) + s3;
  if (q == 0) *(f32x4*)&segtot[wv * 64 + kd0] = tot;
  __syncthreads();
  f32x4 segofs4 = zero, myoff4 = zero;
  #pragma unroll
  for (int i = 0; i < 8; ++i) {
    const f32x4 si = *(const f32x4*)&segtot[i * 64 + kd0];
    if (i < wv) segofs4 += si;
    if (i < 4) myoff4 += si;
  }
  __syncthreads();   // segtot (aliased in rd_s) fully read before rd_s staged
  f32x4 eoff4;
  #pragma unroll
  for (int i = 0; i < 4; ++i) eoff4[i] = __expf(myoff4[i]);

  // ---- pass 2: staging (rd_s, ki_s, vT_s b64; rw->regs; diag->LDS) ----
  short4_t rwq[4];
  {
    f32x4 cc = segofs4 + pre;
    short4_t vb[4];
    float dar[4];
    #pragma unroll
    for (int j = 0; j < 4; ++j) {
      const int t = wv * 16 + q * 4 + j;
      const int addr = t * KD + (((c4 >> 1) ^ (t & 7) ^ ((t >> 3) & 7)) << 3) + (c4 & 1) * 4;
      short4_t rdv, kiv;
      #pragma unroll
      for (int i = 0; i < 4; ++i) {
        const float e1 = __expf(cc[i] - myoff4[i]);
        rdv[i] = (short)f2bf(r4[j][i] * e1);
        rwq[j][i] = (short)f2bf(r4[j][i] * e1 * eoff4[i]);
        kiv[i] = (short)f2bf(k4[j][i] * __expf(myoff4[i] - cc[i] - wl4[j][i]));
        vb[i][j] = (short)f2bf(v4[j][i]);
      }
      *(short4_t*)&rd_s[addr] = rdv;
      *(short4_t*)&ki_s[addr] = kiv;
      dar[j] = r4[j][0] * uk4[0] * k4[j][0];
      dar[j] += r4[j][1] * uk4[1] * k4[j][1];
      dar[j] += r4[j][2] * uk4[2] * k4[j][2];
      dar[j] += r4[j][3] * uk4[3] * k4[j][3];
      cc += wl4[j];
    }
    const int g = wv * 2 + (q >> 1), p4 = (q & 1) * 4;
    #pragma unroll
    for (int i = 0; i < 4; ++i) {
      const int kd = kd0 + i;
      *(short4_t*)&vT_s[kd * TC + ((g ^ (kd & 7)) << 3) + p4] = vb[i];
    }
    // diag: 16-lane butterfly over c4 (cols), 4 rows batched
    #pragma unroll
    for (int o = 8; o > 0; o >>= 1)
      #pragma unroll
      for (int j = 0; j < 4; ++j) dar[j] += __shfl_xor(dar[j], o, 64);
    if (c4 == 0) {
      short4_t dp;
      #pragma unroll
      for (int j = 0; j < 4; ++j) dp[j] = (short)f2bf(dar[j]);
      *(short4_t*)&diag_s[wv * 16 + q * 4] = dp;
    }
  }
  __syncthreads();

  // ---- scan prefix (b128 global reads; issue early, hide under intra) ----
  const int skd = tid >> 3, sv0 = (tid & 7) * 8;
  const size_t sbase = (size_t)bh * (KD * KD);
  float s[8];
  *(f32x4*)&s[0] = *(const f32x4*)&st_in[sbase + skd * KD + sv0];
  *(f32x4*)&s[4] = *(const f32x4*)&st_in[sbase + skd * KD + sv0 + 4];
  const float* wseb = wse_ws + (size_t)bh * N * KD + skd;
  const unsigned short* wkvb = wkv_u16 + (size_t)bh * N * (KD * KD) + skd * KD + sv0;
  {
    float e_c = 0.f; short8 x_c = {0};
    if (n > 0) {
      e_c = wseb[0];
      x_c = *(const short8*)&wkvb[0];
    }
    for (int j = 0; j < n; ++j) {
      const float e = e_c; const short8 x = x_c;
      if (j + 1 < n) {
        e_c = wseb[(size_t)(j + 1) * KD];
        x_c = *(const short8*)&wkvb[(size_t)(j + 1) * (KD * KD)];
      }
      #pragma unroll
      for (int i = 0; i < 8; ++i) s[i] = s[i] * e + bf2f((unsigned short)x[i]);
    }
  }

  // ---- intra: fused A^T tiles + A@v -> oacc regs (one ib per wave) ----
  f32x4 oacc[4];
  {
    const int ib = wv, i0 = ib * 16, irow = i0 + l16;
    const int rsw = (irow & 7) ^ ((irow >> 3) & 7);
    short8 b0 = *(const short8*)&rd_s[irow * KD + ((quad ^ rsw) << 3)];
    short8 b1 = *(const short8*)&rd_s[irow * KD + (((4 + quad) ^ rsw) << 3)];
    const float diag_i = bf2f(diag_s[irow]);
    #pragma unroll
    for (int nn = 0; nn < 4; ++nn) oacc[nn] = (f32x4){0, 0, 0, 0};
    const int npairs = (ib + 2) >> 1;
    // Ast aliases this wave's OWN rd_s segment (rows wv*16..+16, 2048 B >=
    // 1280 B needed). b0/b1 are read before the first Ast write (program
    // order, same wave); no other wave touches this segment.
    unsigned short* astw = &rd_s[wv * 16 * KD];
    for (int jp = 0; jp < npairs; ++jp) {
      #pragma unroll
      for (int jj = 0; jj < 2; ++jj) {
        const int j = jp * 2 + jj;
        short4_t pk;
        if (j <= ib) {
          const int jrow = j * 16 + l16;
          const int jsw = (jrow & 7) ^ ((jrow >> 3) & 7);
          short8 a0 = *(const short8*)&ki_s[jrow * KD + ((quad ^ jsw) << 3)];
          short8 a1 = *(const short8*)&ki_s[jrow * KD + (((4 + quad) ^ jsw) << 3)];
          f32x4 at = {0, 0, 0, 0};
          at = __builtin_amdgcn_mfma_f32_16x16x32_bf16(a0, b0, at, 0, 0, 0);
          at = __builtin_amdgcn_mfma_f32_16x16x32_bf16(a1, b1, at, 0, 0, 0);
          #pragma unroll
          for (int reg = 0; reg < 4; ++reg) {
            const int je = j * 16 + quad * 4 + reg;
            float val = at[reg];
            if (j == ib) val = (je < irow) ? val : ((je == irow) ? diag_i : 0.f);
            pk[reg] = (short)f2bf(val);
          }
        } else {
          pk = (short4_t)0;  // guard half for even ib
        }
        *(short4_t*)&astw[l16 * 40 + jj * 16 + quad * 4] = pk;
      }
      short8 af = *(const short8*)&astw[l16 * 40 + quad * 8];
      #pragma unroll
      for (int nn = 0; nn < 4; ++nn) {
        const int vd = nn * 16 + l16;
        short8 bv = *(const short8*)&vT_s[vd * TC + (((jp * 4 + quad) ^ (vd & 7)) << 3)];
        oacc[nn] = __builtin_amdgcn_mfma_f32_16x16x32_bf16(af, bv, oacc[nn], 0, 0, 0);
      }
    }
  }
  __syncthreads();   // staging LDS dead; safe to repurpose

  // ---- sT -> ki_s[0..4096), rw regs -> rd_s (swizzled b64) ----
  {
    const int g = skd >> 3, k7 = skd & 7;
    #pragma unroll
    for (int i = 0; i < 8; ++i) {
      const int vd = sv0 + i;
      ki_s[vd * KD + (((g ^ (vd & 7)) << 3) | k7)] = f2bf(s[i]);
    }
  }
  #pragma unroll
  for (int j = 0; j < 4; ++j) {
    const int t = wv * 16 + q * 4 + j;
    const int addr = t * KD + (((c4 >> 1) ^ (t & 7) ^ ((t >> 3) & 7)) << 3) + (c4 & 1) * 4;
    *(short4_t*)&rd_s[addr] = rwq[j];
  }
  if (n == N - 1) {   // final state: one more step then store
    const float e = wseb[(size_t)n * KD];
    const short8 x = *(const short8*)&wkvb[(size_t)n * (KD * KD)];
    #pragma unroll
    for (int i = 0; i < 8; ++i) s[i] = s[i] * e + bf2f((unsigned short)x[i]);
    *(f32x4*)&final_out[sbase + skd * KD + sv0] = *(const f32x4*)&s[0];
    *(f32x4*)&final_out[sbase + skd * KD + sv0 + 4] = *(const f32x4*)&s[4];
  }
  __syncthreads();

  // ---- inter = rw @ S_n; out = intra + inter, single pure-write store ----
  {
    const int ib = wv, trow = ib * 16 + l16;
    const int rsw = (trow & 7) ^ ((trow >> 3) & 7);
    short8 a0 = *(const short8*)&rd_s[trow * KD + ((quad ^ rsw) << 3)];
    short8 a1 = *(const short8*)&rd_s[trow * KD + (((4 + quad) ^ rsw) << 3)];
    float* og = out + base;
    #pragma unroll
    for (int nn = 0; nn < 4; ++nn) {
      const int vd = nn * 16 + l16;
      short8 b0 = *(const short8*)&ki_s[vd * KD + ((quad ^ (vd & 7)) << 3)];
      short8 b1 = *(const short8*)&ki_s[vd * KD + (((4 + quad) ^ (vd & 7)) << 3)];
      f32x4 acc = {0, 0, 0, 0};
      acc = __builtin_amdgcn_mfma_f32_16x16x32_bf16(a0, b0, acc, 0, 0, 0);
      acc = __builtin_amdgcn_mfma_f32_16x16x32_bf16(a1, b1, acc, 0, 0, 0);
      #pragma unroll
      for (int reg = 0; reg < 4; ++reg)
        og[(size_t)(ib * 16 + quad * 4 + reg) * KD + nn * 16 + l16] = oacc[nn][reg] + acc[reg];
    }
  }
}

// ---------------------------------------------------------------------------
// Workspace (~8.9 MB): [wkv u16: BH*N*K*K][wse f32: BH*N*K]
// ---------------------------------------------------------------------------
extern "C" void kernel_launch(void* const* d_in, const int* in_sizes, int n_in,
                              void* d_out, int out_size, void* d_ws, size_t ws_size,
                              hipStream_t stream) {
  const float* r = (const float*)d_in[0];
  const float* k = (const float*)d_in[1];
  const float* v = (const float*)d_in[2];
  const float* w = (const float*)d_in[3];
  const float* u = (const float*)d_in[4];
  const float* st0 = (const float*)d_in[5];
  float* out = (float*)d_out;

  const int BH = in_sizes[5] / (KD * KD);  // 64
  const int H = in_sizes[4] / KD;          // 16
  const int T = in_sizes[0] / (BH * KD);   // 2048
  const int N = T / TC;                    // 16

  unsigned short* wkv_u16 = (unsigned short*)d_ws;
  float* wse_ws = (float*)(wkv_u16 + (size_t)BH * N * KD * KD);
  float* final_out = out + (size_t)in_sizes[0];

  rwkv_wkv<<<BH * N, 512, 0, stream>>>(k, v, w, wkv_u16, wse_ws, N);
  rwkv_main<<<BH * N, 512, 0, stream>>>(r, k, v, w, u, wkv_u16, wse_ws, st0,
                                        out, final_out, H, N);
}

// Round 11
// 196.629 us; speedup vs baseline: 1.3089x; 1.0943x over previous
//
#include <hip/hip_runtime.h>

#define TC 128
#define KD 64
#define WLOG_MIN (-5.2983174f)   // ln(0.005)

typedef __attribute__((ext_vector_type(8))) short short8;
typedef __attribute__((ext_vector_type(4))) short short4_t;
typedef __attribute__((ext_vector_type(4))) float f32x4;

__device__ __forceinline__ unsigned short f2bf(float x) {
  union { float f; unsigned int u; } c; c.f = x;
  unsigned int u = c.u + 0x7fffu + ((c.u >> 16) & 1u);   // RNE
  return (unsigned short)(u >> 16);
}
__device__ __forceinline__ float bf2f(unsigned short x) {
  union { unsigned int u; float f; } c; c.u = ((unsigned int)x) << 16; return c.f;
}
__device__ __forceinline__ f32x4 shfl4(f32x4 v, int src) {
  f32x4 r;
  #pragma unroll
  for (int i = 0; i < 4; ++i) r[i] = __shfl(v[i], src, 64);
  return r;
}

// Staging thread map (both kernels): lane = (q = lane>>4, c4 = lane&15).
// Lane owns cols kd0..kd0+3 (kd0 = c4*4) x rows t = wv*16 + q*4 + j (j<4).
// -> ALL input loads are global_load_dwordx4 (1 KB/wave/instr).
// REGISTER BUDGET (rounds 9-10 lesson): the staged f32x4 arrays (~60 live
// VGPRs) spill to scratch under BOTH the 64-reg cap (512,8) AND the 85-reg
// cap (512,6) — measured VGPR=40 + ~95 MB scratch traffic both times.
// ONLY (512,4) (128-reg cap) allocates spill-free (round 10: main 85->~40
// us). Both kernels therefore use (512,4); 2 blocks/CU, 16 waves/CU.
// rd/ki swizzle: elem (t,kd) at t*64 + (slot<<3 | kd&7),
//   slot = (kd>>3)^(t&7)^((t>>3)&7); per-lane 4 cols = one b64 store.
// vT/kiT/sT swizzle: (t,kd) at kd*TC + ((g^(kd&7))<<3) + (t&7), g=t>>3.
// Cumsum: in-lane serial over 4 rows + quad-prefix via shfl (ulp-level
// addition-order change vs serial-16; threshold headroom 0.25/0.775).

// ---------------------------------------------------------------------------
// K1 (wkv/wse producer): per-(b,h,chunk), 512 thr. dwordx4 loads of k,v,w;
// stages kiT/vT; 2 wkv tiles per wave; writes wkv bf16 + wse.
// ---------------------------------------------------------------------------
__global__ __launch_bounds__(512, 4)
void rwkv_wkv(const float* __restrict__ kk_, const float* __restrict__ vv,
              const float* __restrict__ ww,
              unsigned short* __restrict__ wkv_u16, float* __restrict__ wse_ws,
              int N) {
  __shared__ alignas(16) unsigned short vT_s[KD * TC];
  __shared__ alignas(16) unsigned short kiT_s[KD * TC];
  __shared__ alignas(16) float segtot[8 * 64];

  const int bid = blockIdx.x;
  const int n = bid % N, bh = bid / N;
  const size_t base = ((size_t)bh * N + n) * (TC * KD);
  const float *kg = kk_ + base, *vg = vv + base, *wg = ww + base;

  const int tid = threadIdx.x;
  const int lane = tid & 63, wv = tid >> 6;
  const int q = lane >> 4, c4 = lane & 15, kd0 = c4 * 4;

  // ---- dwordx4 loads ----
  f32x4 wl4[4], k4[4], v4[4];
  #pragma unroll
  for (int j = 0; j < 4; ++j) {
    const int t = wv * 16 + q * 4 + j;
    wl4[j] = *(const f32x4*)&wg[t * KD + kd0];
    k4[j] = *(const f32x4*)&kg[t * KD + kd0];
    v4[j] = *(const f32x4*)&vg[t * KD + kd0];
  }
  #pragma unroll
  for (int j = 0; j < 4; ++j)
    #pragma unroll
    for (int i = 0; i < 4; ++i) wl4[j][i] = fmaxf(wl4[j][i], WLOG_MIN);

  // ---- pass 1: in-lane serial col-sums + quad prefix/totals via shfl ----
  const f32x4 ls = ((wl4[0] + wl4[1]) + wl4[2]) + wl4[3];
  const f32x4 s0 = shfl4(ls, c4), s1 = shfl4(ls, 16 + c4);
  const f32x4 s2 = shfl4(ls, 32 + c4), s3 = shfl4(ls, 48 + c4);
  const f32x4 zero = {0.f, 0.f, 0.f, 0.f};
  f32x4 pre = (q > 0 ? s0 : zero);
  pre += (q > 1 ? s1 : zero);
  pre += (q > 2 ? s2 : zero);
  const f32x4 tot = ((s0 + s1) + s2) + s3;
  if (q == 0) *(f32x4*)&segtot[wv * 64 + kd0] = tot;
  __syncthreads();

  f32x4 segofs4 = zero, myoff4 = zero, wsum4 = zero;
  #pragma unroll
  for (int i = 0; i < 8; ++i) {
    const f32x4 si = *(const f32x4*)&segtot[i * 64 + kd0];
    if (i < wv) segofs4 += si;
    if (i < 4) myoff4 += si;
    wsum4 += si;
  }
  f32x4 wsoff4;
  #pragma unroll
  for (int i = 0; i < 4; ++i) wsoff4[i] = __expf(wsum4[i] - myoff4[i]);
  if (wv == 0 && q == 0) {
    f32x4 e;
    #pragma unroll
    for (int i = 0; i < 4; ++i) e[i] = __expf(wsum4[i]);
    *(f32x4*)&wse_ws[((size_t)bh * N + n) * KD + kd0] = e;
  }

  // ---- pass 2: stage ki^T, v^T (b64 stores) ----
  {
    f32x4 cc = segofs4 + pre;
    short4_t kib[4], vb[4];
    #pragma unroll
    for (int j = 0; j < 4; ++j) {
      #pragma unroll
      for (int i = 0; i < 4; ++i) {
        kib[i][j] = (short)f2bf(k4[j][i] * __expf(myoff4[i] - cc[i] - wl4[j][i]));
        vb[i][j] = (short)f2bf(v4[j][i]);
      }
      cc += wl4[j];
    }
    const int g = wv * 2 + (q >> 1), p4 = (q & 1) * 4;
    #pragma unroll
    for (int i = 0; i < 4; ++i) {
      const int kd = kd0 + i;
      *(short4_t*)&kiT_s[kd * TC + ((g ^ (kd & 7)) << 3) + p4] = kib[i];
      *(short4_t*)&vT_s[kd * TC + ((g ^ (kd & 7)) << 3) + p4] = vb[i];
    }
  }
  __syncthreads();

  // ---- wkv = (ki * w_inter)^T @ v -> bf16 (2 of 16 tiles per wave) ----
  {
    const int quad = lane >> 4, l16 = lane & 15;
    const int kt = wv >> 1;             // kd-tile 0..3
    const int nb = (wv & 1) * 2;        // vd-tile base
    f32x4 acc[2] = {{0,0,0,0},{0,0,0,0}};
    const int row = kt * 16 + l16;      // kd row of ki^T
    #pragma unroll
    for (int ks = 0; ks < 4; ++ks) {
      short8 a = *(const short8*)&kiT_s[row * TC + (((ks * 4 + quad) ^ (row & 7)) << 3)];
      #pragma unroll
      for (int nn = 0; nn < 2; ++nn) {
        const int vd = (nb + nn) * 16 + l16;
        short8 b = *(const short8*)&vT_s[vd * TC + (((ks * 4 + quad) ^ (vd & 7)) << 3)];
        acc[nn] = __builtin_amdgcn_mfma_f32_16x16x32_bf16(a, b, acc[nn], 0, 0, 0);
      }
    }
    // col x = kt*16+quad*4+reg lives at lane x>>2 = kt*4+quad, comp x&3 = reg
    float wso[4];
    #pragma unroll
    for (int reg = 0; reg < 4; ++reg) wso[reg] = __shfl(wsoff4[reg], kt * 4 + quad, 64);
    unsigned short* wkvg = wkv_u16 + ((size_t)bh * N + n) * (KD * KD);
    #pragma unroll
    for (int nn = 0; nn < 2; ++nn)
      #pragma unroll
      for (int reg = 0; reg < 4; ++reg)
        wkvg[(kt * 16 + quad * 4 + reg) * KD + (nb + nn) * 16 + l16] = f2bf(acc[nn][reg] * wso[reg]);
  }
}

// ---------------------------------------------------------------------------
// K2 (main): per-(b,h,chunk), 512 thr. dwordx4 loads of r/k/v/w; intra A@v
// -> regs; scans wkv prefix (L3-hot) -> S_n; out = intra + rw@S_n, single
// pure-write store. segtot + Ast alias dead regions of rd_s.
// LDS 49,408 B; (512,4): 128-reg cap -> no spill, 2 blocks/CU.
// ---------------------------------------------------------------------------
__global__ __launch_bounds__(512, 4)
void rwkv_main(const float* __restrict__ rr, const float* __restrict__ kk_,
               const float* __restrict__ vv, const float* __restrict__ ww,
               const float* __restrict__ uu,
               const unsigned short* __restrict__ wkv_u16,
               const float* __restrict__ wse_ws,
               const float* __restrict__ st_in,
               float* __restrict__ out, float* __restrict__ final_out,
               int H, int N) {
  __shared__ alignas(16) unsigned short rd_s[TC * KD];  // aliases segtot + per-wave Ast
  __shared__ alignas(16) unsigned short ki_s[TC * KD];
  __shared__ alignas(16) unsigned short vT_s[KD * TC];
  __shared__ alignas(16) unsigned short diag_s[TC];
  float* segtot = (float*)rd_s;   // pass-1 only; consumed before rd_s staged

  const int bid = blockIdx.x;
  const int n = bid % N, bh = bid / N, h = bh % H;
  const size_t base = ((size_t)bh * N + n) * (TC * KD);
  const float *rg = rr + base, *kg = kk_ + base, *vg = vv + base, *wg = ww + base;

  const int tid = threadIdx.x;
  const int lane = tid & 63, wv = tid >> 6;
  const int q = lane >> 4, c4 = lane & 15, kd0 = c4 * 4;
  const int quad = lane >> 4, l16 = lane & 15;
  const f32x4 uk4 = *(const f32x4*)&uu[h * KD + kd0];

  // ---- dwordx4 loads ----
  f32x4 wl4[4], r4[4], k4[4], v4[4];
  #pragma unroll
  for (int j = 0; j < 4; ++j) {
    const int t = wv * 16 + q * 4 + j;
    wl4[j] = *(const f32x4*)&wg[t * KD + kd0];
    r4[j] = *(const f32x4*)&rg[t * KD + kd0];
    k4[j] = *(const f32x4*)&kg[t * KD + kd0];
    v4[j] = *(const f32x4*)&vg[t * KD + kd0];
  }
  #pragma unroll
  for (int j = 0; j < 4; ++j)
    #pragma unroll
    for (int i = 0; i < 4; ++i) wl4[j][i] = fmaxf(wl4[j][i], WLOG_MIN);

  // ---- pass 1 ----
  const f32x4 ls = ((wl4[0] + wl4[1]) + wl4[2]) + wl4[3];
  const f32x4 s0 = shfl4(ls, c4), s1 = shfl4(ls, 16 + c4);
  const f32x4 s2 = shfl4(ls, 32 + c4), s3 = shfl4(ls, 48 + c4);
  const f32x4 zero = {0.f, 0.f, 0.f, 0.f};
  f32x4 pre = (q > 0 ? s0 : zero);
  pre += (q > 1 ? s1 : zero);
  pre += (q > 2 ? s2 : zero);
  const f32x4 tot = ((s0 + s1) + s2) + s3;
  if (q == 0) *(f32x4*)&segtot[wv * 64 + kd0] = tot;
  __syncthreads();
  f32x4 segofs4 = zero, myoff4 = zero;
  #pragma unroll
  for (int i = 0; i < 8; ++i) {
    const f32x4 si = *(const f32x4*)&segtot[i * 64 + kd0];
    if (i < wv) segofs4 += si;
    if (i < 4) myoff4 += si;
  }
  __syncthreads();   // segtot (aliased in rd_s) fully read before rd_s staged
  f32x4 eoff4;
  #pragma unroll
  for (int i = 0; i < 4; ++i) eoff4[i] = __expf(myoff4[i]);

  // ---- pass 2: staging (rd_s, ki_s, vT_s b64; rw->regs; diag->LDS) ----
  short4_t rwq[4];
  {
    f32x4 cc = segofs4 + pre;
    short4_t vb[4];
    float dar[4];
    #pragma unroll
    for (int j = 0; j < 4; ++j) {
      const int t = wv * 16 + q * 4 + j;
      const int addr = t * KD + (((c4 >> 1) ^ (t & 7) ^ ((t >> 3) & 7)) << 3) + (c4 & 1) * 4;
      short4_t rdv, kiv;
      #pragma unroll
      for (int i = 0; i < 4; ++i) {
        const float e1 = __expf(cc[i] - myoff4[i]);
        rdv[i] = (short)f2bf(r4[j][i] * e1);
        rwq[j][i] = (short)f2bf(r4[j][i] * e1 * eoff4[i]);
        kiv[i] = (short)f2bf(k4[j][i] * __expf(myoff4[i] - cc[i] - wl4[j][i]));
        vb[i][j] = (short)f2bf(v4[j][i]);
      }
      *(short4_t*)&rd_s[addr] = rdv;
      *(short4_t*)&ki_s[addr] = kiv;
      dar[j] = r4[j][0] * uk4[0] * k4[j][0];
      dar[j] += r4[j][1] * uk4[1] * k4[j][1];
      dar[j] += r4[j][2] * uk4[2] * k4[j][2];
      dar[j] += r4[j][3] * uk4[3] * k4[j][3];
      cc += wl4[j];
    }
    const int g = wv * 2 + (q >> 1), p4 = (q & 1) * 4;
    #pragma unroll
    for (int i = 0; i < 4; ++i) {
      const int kd = kd0 + i;
      *(short4_t*)&vT_s[kd * TC + ((g ^ (kd & 7)) << 3) + p4] = vb[i];
    }
    // diag: 16-lane butterfly over c4 (cols), 4 rows batched
    #pragma unroll
    for (int o = 8; o > 0; o >>= 1)
      #pragma unroll
      for (int j = 0; j < 4; ++j) dar[j] += __shfl_xor(dar[j], o, 64);
    if (c4 == 0) {
      short4_t dp;
      #pragma unroll
      for (int j = 0; j < 4; ++j) dp[j] = (short)f2bf(dar[j]);
      *(short4_t*)&diag_s[wv * 16 + q * 4] = dp;
    }
  }
  __syncthreads();

  // ---- scan prefix (b128 global reads; issue early, hide under intra) ----
  const int skd = tid >> 3, sv0 = (tid & 7) * 8;
  const size_t sbase = (size_t)bh * (KD * KD);
  float s[8];
  *(f32x4*)&s[0] = *(const f32x4*)&st_in[sbase + skd * KD + sv0];
  *(f32x4*)&s[4] = *(const f32x4*)&st_in[sbase + skd * KD + sv0 + 4];
  const float* wseb = wse_ws + (size_t)bh * N * KD + skd;
  const unsigned short* wkvb = wkv_u16 + (size_t)bh * N * (KD * KD) + skd * KD + sv0;
  {
    float e_c = 0.f; short8 x_c = {0};
    if (n > 0) {
      e_c = wseb[0];
      x_c = *(const short8*)&wkvb[0];
    }
    for (int j = 0; j < n; ++j) {
      const float e = e_c; const short8 x = x_c;
      if (j + 1 < n) {
        e_c = wseb[(size_t)(j + 1) * KD];
        x_c = *(const short8*)&wkvb[(size_t)(j + 1) * (KD * KD)];
      }
      #pragma unroll
      for (int i = 0; i < 8; ++i) s[i] = s[i] * e + bf2f((unsigned short)x[i]);
    }
  }

  // ---- intra: fused A^T tiles + A@v -> oacc regs (one ib per wave) ----
  f32x4 oacc[4];
  {
    const int ib = wv, i0 = ib * 16, irow = i0 + l16;
    const int rsw = (irow & 7) ^ ((irow >> 3) & 7);
    short8 b0 = *(const short8*)&rd_s[irow * KD + ((quad ^ rsw) << 3)];
    short8 b1 = *(const short8*)&rd_s[irow * KD + (((4 + quad) ^ rsw) << 3)];
    const float diag_i = bf2f(diag_s[irow]);
    #pragma unroll
    for (int nn = 0; nn < 4; ++nn) oacc[nn] = (f32x4){0, 0, 0, 0};
    const int npairs = (ib + 2) >> 1;
    // Ast aliases this wave's OWN rd_s segment (rows wv*16..+16, 2048 B >=
    // 1280 B needed). b0/b1 are read before the first Ast write (program
    // order, same wave); no other wave touches this segment.
    unsigned short* astw = &rd_s[wv * 16 * KD];
    for (int jp = 0; jp < npairs; ++jp) {
      #pragma unroll
      for (int jj = 0; jj < 2; ++jj) {
        const int j = jp * 2 + jj;
        short4_t pk;
        if (j <= ib) {
          const int jrow = j * 16 + l16;
          const int jsw = (jrow & 7) ^ ((jrow >> 3) & 7);
          short8 a0 = *(const short8*)&ki_s[jrow * KD + ((quad ^ jsw) << 3)];
          short8 a1 = *(const short8*)&ki_s[jrow * KD + (((4 + quad) ^ jsw) << 3)];
          f32x4 at = {0, 0, 0, 0};
          at = __builtin_amdgcn_mfma_f32_16x16x32_bf16(a0, b0, at, 0, 0, 0);
          at = __builtin_amdgcn_mfma_f32_16x16x32_bf16(a1, b1, at, 0, 0, 0);
          #pragma unroll
          for (int reg = 0; reg < 4; ++reg) {
            const int je = j * 16 + quad * 4 + reg;
            float val = at[reg];
            if (j == ib) val = (je < irow) ? val : ((je == irow) ? diag_i : 0.f);
            pk[reg] = (short)f2bf(val);
          }
        } else {
          pk = (short4_t)0;  // guard half for even ib
        }
        *(short4_t*)&astw[l16 * 40 + jj * 16 + quad * 4] = pk;
      }
      short8 af = *(const short8*)&astw[l16 * 40 + quad * 8];
      #pragma unroll
      for (int nn = 0; nn < 4; ++nn) {
        const int vd = nn * 16 + l16;
        short8 bv = *(const short8*)&vT_s[vd * TC + (((jp * 4 + quad) ^ (vd & 7)) << 3)];
        oacc[nn] = __builtin_amdgcn_mfma_f32_16x16x32_bf16(af, bv, oacc[nn], 0, 0, 0);
      }
    }
  }
  __syncthreads();   // staging LDS dead; safe to repurpose

  // ---- sT -> ki_s[0..4096), rw regs -> rd_s (swizzled b64) ----
  {
    const int g = skd >> 3, k7 = skd & 7;
    #pragma unroll
    for (int i = 0; i < 8; ++i) {
      const int vd = sv0 + i;
      ki_s[vd * KD + (((g ^ (vd & 7)) << 3) | k7)] = f2bf(s[i]);
    }
  }
  #pragma unroll
  for (int j = 0; j < 4; ++j) {
    const int t = wv * 16 + q * 4 + j;
    const int addr = t * KD + (((c4 >> 1) ^ (t & 7) ^ ((t >> 3) & 7)) << 3) + (c4 & 1) * 4;
    *(short4_t*)&rd_s[addr] = rwq[j];
  }
  if (n == N - 1) {   // final state: one more step then store
    const float e = wseb[(size_t)n * KD];
    const short8 x = *(const short8*)&wkvb[(size_t)n * (KD * KD)];
    #pragma unroll
    for (int i = 0; i < 8; ++i) s[i] = s[i] * e + bf2f((unsigned short)x[i]);
    *(f32x4*)&final_out[sbase + skd * KD + sv0] = *(const f32x4*)&s[0];
    *(f32x4*)&final_out[sbase + skd * KD + sv0 + 4] = *(const f32x4*)&s[4];
  }
  __syncthreads();

  // ---- inter = rw @ S_n; out = intra + inter, single pure-write store ----
  {
    const int ib = wv, trow = ib * 16 + l16;
    const int rsw = (trow & 7) ^ ((trow >> 3) & 7);
    short8 a0 = *(const short8*)&rd_s[trow * KD + ((quad ^ rsw) << 3)];
    short8 a1 = *(const short8*)&rd_s[trow * KD + (((4 + quad) ^ rsw) << 3)];
    float* og = out + base;
    #pragma unroll
    for (int nn = 0; nn < 4; ++nn) {
      const int vd = nn * 16 + l16;
      short8 b0 = *(const short8*)&ki_s[vd * KD + ((quad ^ (vd & 7)) << 3)];
      short8 b1 = *(const short8*)&ki_s[vd * KD + (((4 + quad) ^ (vd & 7)) << 3)];
      f32x4 acc = {0, 0, 0, 0};
      acc = __builtin_amdgcn_mfma_f32_16x16x32_bf16(a0, b0, acc, 0, 0, 0);
      acc = __builtin_amdgcn_mfma_f32_16x16x32_bf16(a1, b1, acc, 0, 0, 0);
      #pragma unroll
      for (int reg = 0; reg < 4; ++reg)
        og[(size_t)(ib * 16 + quad * 4 + reg) * KD + nn * 16 + l16] = oacc[nn][reg] + acc[reg];
    }
  }
}

// ---------------------------------------------------------------------------
// Workspace (~8.9 MB): [wkv u16: BH*N*K*K][wse f32: BH*N*K]
// ---------------------------------------------------------------------------
extern "C" void kernel_launch(void* const* d_in, const int* in_sizes, int n_in,
                              void* d_out, int out_size, void* d_ws, size_t ws_size,
                              hipStream_t stream) {
  const float* r = (const float*)d_in[0];
  const float* k = (const float*)d_in[1];
  const float* v = (const float*)d_in[2];
  const float* w = (const float*)d_in[3];
  const float* u = (const float*)d_in[4];
  const float* st0 = (const float*)d_in[5];
  float* out = (float*)d_out;

  const int BH = in_sizes[5] / (KD * KD);  // 64
  const int H = in_sizes[4] / KD;          // 16
  const int T = in_sizes[0] / (BH * KD);   // 2048
  const int N = T / TC;                    // 16

  unsigned short* wkv_u16 = (unsigned short*)d_ws;
  float* wse_ws = (float*)(wkv_u16 + (size_t)BH * N * KD * KD);
  float* final_out = out + (size_t)in_sizes[0];

  rwkv_wkv<<<BH * N, 512, 0, stream>>>(k, v, w, wkv_u16, wse_ws, N);
  rwkv_main<<<BH * N, 512, 0, stream>>>(r, k, v, w, u, wkv_u16, wse_ws, st0,
                                        out, final_out, H, N);
}